// Round 2
// baseline (693.588 us; speedup 1.0000x reference)
//
#include <hip/hip_runtime.h>
#include <math.h>

#define H_ 128
#define W_ 128
#define C_ 64
#define O_ 64
#define B_ 8
#define K2_ 9
#define HWSZ (H_*W_)
#define ROWS_ 30          // staged x window rows per channel (covers |offset|<=12)

// ---------------------------------------------------------------------------
// Kernel P: weight prep.
//  wt  (K2, C, O)  : sample-GEMM weights, contiguous in o -> clean s_load.
//  wom (C, 27, 9)  : offset(18)+mask(9) conv weights contiguous per channel.
// ---------------------------------------------------------------------------
__global__ __launch_bounds__(256) void prep_weights_k(
    const float* __restrict__ w, const float* __restrict__ w_off,
    const float* __restrict__ w_mod, float* __restrict__ wt,
    float* __restrict__ wom) {
    int id = blockIdx.x * 256 + threadIdx.x;
    if (id < K2_ * C_ * O_) {              // id = k*C*O + c*O + o
        int o = id & (O_ - 1);
        int c = (id >> 6) & (C_ - 1);
        int k = id / (C_ * O_);
        wt[id] = w[(o * C_ + c) * K2_ + k];
    }
    int id2 = id - K2_ * C_ * O_;
    if (id2 >= 0 && id2 < C_ * 243) {      // id2 = c*243 + t*9 + k
        int k = id2 % 9;
        int tt = (id2 / 9) % 27;
        int c = id2 / 243;
        float v = (tt < 18) ? w_off[(tt * C_ + c) * K2_ + k]
                            : w_mod[((tt - 18) * C_ + c) * K2_ + k];
        wom[id2] = v;
    }
}

// ---------------------------------------------------------------------------
// Kernel A: 3x3 conv -> 18 offset + 9 mask channels, fused coord calc.
// (unchanged from round 1 -- it improved: non-B time 191 -> 128 us)
// ---------------------------------------------------------------------------
__global__ __launch_bounds__(512) void conv_offmask_k(
    const float* __restrict__ x,
    const float* __restrict__ wom, const float* __restrict__ b_off,
    const float* __restrict__ b_mod,
    float* __restrict__ pyA, float* __restrict__ pxA, float* __restrict__ mA) {
    __shared__ float red[27 * 128];        // 13.8 KB

    int b     = blockIdx.x & 7;            // batch -> XCD (L2 locality)
    int strip = blockIdx.x >> 3;           // 0..127 : 1-row strip
    int tid   = threadIdx.x;
    int t     = tid & 127;                 // pixel within strip
    int q     = tid >> 7;                  // 0..3 -> channel quarter
    int c0    = __builtin_amdgcn_readfirstlane(q << 4);  // wave-uniform SGPR
    int p     = strip * 128 + t;
    int w     = p & (W_ - 1);
    int h     = p >> 7;

    int offs[9];
    float valid[9];
#pragma unroll
    for (int i = 0; i < 9; i++) {
        int dy = i / 3 - 1, dx = i % 3 - 1;
        int yy = h + dy, xx = w + dx;
        bool v = (yy >= 0 && yy < H_ && xx >= 0 && xx < W_);
        int yc = min(max(yy, 0), H_ - 1);
        int xc = min(max(xx, 0), W_ - 1);
        offs[i] = yc * W_ + xc;
        valid[i] = v ? 1.0f : 0.0f;
    }

    float acc[27];
#pragma unroll
    for (int o = 0; o < 27; o++) acc[o] = 0.0f;

    const float* xb = x + (b * C_ + c0) * HWSZ;

    float v[9];
#pragma unroll
    for (int i = 0; i < 9; i++) v[i] = xb[offs[i]] * valid[i];

    for (int c = 0; c < 16; c++) {
        const float* xn = xb + min(c + 1, 15) * HWSZ;
        float vn[9];
#pragma unroll
        for (int i = 0; i < 9; i++) vn[i] = xn[offs[i]] * valid[i];

        const float* wc = wom + (c0 + c) * 243;   // uniform -> s_load stream
#pragma unroll
        for (int o = 0; o < 27; o++) {
#pragma unroll
            for (int kk = 0; kk < 9; kk++) acc[o] += v[kk] * wc[o * 9 + kk];
        }
#pragma unroll
        for (int i = 0; i < 9; i++) v[i] = vn[i];
    }

    if (q == 3) {
#pragma unroll
        for (int o = 0; o < 27; o++) red[o * 128 + t] = acc[o];
    }
    __syncthreads();
    if (q == 2) {
#pragma unroll
        for (int o = 0; o < 27; o++) red[o * 128 + t] += acc[o];
    }
    __syncthreads();
    if (q == 1) {
#pragma unroll
        for (int o = 0; o < 27; o++) red[o * 128 + t] += acc[o];
    }
    __syncthreads();
    if (q == 0) {
#pragma unroll
        for (int k = 0; k < 9; k++) {
            float dy = acc[2 * k]     + red[(2 * k)     * 128 + t] + b_off[2 * k];
            float dx = acc[2 * k + 1] + red[(2 * k + 1) * 128 + t] + b_off[2 * k + 1];
            float mm = acc[18 + k]    + red[(18 + k)    * 128 + t] + b_mod[k];
            float mask = 2.0f / (1.0f + __expf(-mm));
            float py = dy + (float)h - 1.0f + (float)(k / 3);
            float px = dx + (float)w - 1.0f + (float)(k % 3);
            int idx = (b * 9 + k) * HWSZ + p;
            pyA[idx] = py;
            pxA[idx] = px;
            mA[idx] = mask;
        }
    }
}

// ---------------------------------------------------------------------------
// Kernel B v3: bilinear sample + masked reduction GEMM, LDS-staged x.
// Round-1 lesson: time is linear in GLOBAL gather count (o-split doubled
// gathers -> exactly 2x slower); k-outer/c-inner streams 256KB/k through the
// 32KB L1 so every gather L1-misses (~31 cyc/instr observed). Fix: stage a
// 30-row x window (4 channels at a time, 60KB LDS) with coalesced float4
// copies; gather via ds_read_b32 (~6 cyc, lanes read consecutive cols ->
// conflict-free). Offsets have std 1.2, max ~6; window covers |dy|<=12.
// Correctness does NOT depend on the window: per-lane cold path re-gathers
// from global when a tap's row falls outside (execz-skipped when unused).
// Block = 256 threads = 256 pixels (2 rows), each thread owns all 64 outputs.
// 2 blocks/CU (LDS-capped); no inter-thread reduce, no gather duplication.
// ---------------------------------------------------------------------------
__global__ __launch_bounds__(256) void sample_gemm_k(
    const float* __restrict__ x,
    const float* __restrict__ pyA, const float* __restrict__ pxA,
    const float* __restrict__ mA, const float* __restrict__ wt,
    const float* __restrict__ bias, float* __restrict__ out) {
    __shared__ float lbuf[4 * ROWS_ * W_];   // 61,440 B

    int b     = blockIdx.x & 7;              // batch -> XCD (L2 locality)
    int strip = blockIdx.x >> 3;             // 0..63 : 2-row strip
    int t     = threadIdx.x;                 // 256 threads = 256 pixels
    int p     = strip * 256 + t;
    int w     = p & (W_ - 1);
    int h     = p >> 7;
    (void)w; (void)h;
    int h0    = strip * 2;

    int lo   = max(0, h0 - 14);
    int hi   = min(H_ - 1, h0 + 15);
    int rows = hi - lo + 1;                  // <= 30

    float acc[O_];
#pragma unroll
    for (int o = 0; o < O_; o++) acc[o] = 0.0f;

    const float* xb = x + b * C_ * HWSZ;

    for (int ch = 0; ch < 16; ch++) {
        __syncthreads();                     // protect lbuf from prior readers
        // ---- stage 4 channels x rows*128 floats (contiguous rows) ----
        int nf4 = rows * (W_ / 4);           // float4 count per channel
#pragma unroll
        for (int cc = 0; cc < 4; cc++) {
            const float4* s4 = (const float4*)(xb + (ch * 4 + cc) * HWSZ + lo * W_);
            float4* d4 = (float4*)(lbuf + cc * (ROWS_ * W_));
            for (int i = t; i < nf4; i += 256) d4[i] = s4[i];
        }
        __syncthreads();

        for (int k = 0; k < 9; k++) {
            int idx = (b * 9 + k) * HWSZ + p;
            float py = pyA[idx], px = pxA[idx], m = mA[idx];   // L1-hot after ch=0

            float y0f = floorf(py), x0f = floorf(px);
            float wy = py - y0f, wx = px - x0f;
            int y0 = (int)y0f, x0 = (int)x0f;
            int y1 = y0 + 1, x1 = x0 + 1;
            float vy0 = (y0 >= 0 && y0 < H_) ? 1.0f : 0.0f;
            float vy1 = (y1 >= 0 && y1 < H_) ? 1.0f : 0.0f;
            float vx0 = (x0 >= 0 && x0 < W_) ? 1.0f : 0.0f;
            float vx1 = (x1 >= 0 && x1 < W_) ? 1.0f : 0.0f;
            int y0c = min(max(y0, 0), H_ - 1), y1c = min(max(y1, 0), H_ - 1);
            int x0c = min(max(x0, 0), W_ - 1), x1c = min(max(x1, 0), W_ - 1);

            float w00 = (1.0f - wy) * (1.0f - wx) * vy0 * vx0 * m;
            float w01 = (1.0f - wy) * wx * vy0 * vx1 * m;
            float w10 = wy * (1.0f - wx) * vy1 * vx0 * m;
            float w11 = wy * wx * vy1 * vx1 * m;

            int ly0 = y0c - lo, ly1 = y1c - lo;
            bool i0 = (unsigned)ly0 < (unsigned)rows;   // row in staged window?
            bool i1 = (unsigned)ly1 < (unsigned)rows;
            int c0r = min(max(ly0, 0), rows - 1);       // safe LDS row
            int c1r = min(max(ly1, 0), rows - 1);
            int a00 = c0r * W_ + x0c, a01 = c0r * W_ + x1c;
            int a10 = c1r * W_ + x0c, a11 = c1r * W_ + x1c;

            const float* wpk = wt + k * (C_ * O_) + (ch * 4) * O_;  // uniform
#pragma unroll
            for (int cc = 0; cc < 4; cc++) {
                const float* L = lbuf + cc * (ROWS_ * W_);
                float v00 = L[a00], v01 = L[a01];
                float v10 = L[a10], v11 = L[a11];
                if (__builtin_expect(!i0, 0)) {          // cold: outside window
                    const float* xc = xb + (ch * 4 + cc) * HWSZ + y0c * W_;
                    v00 = xc[x0c]; v01 = xc[x1c];
                }
                if (__builtin_expect(!i1, 0)) {
                    const float* xc = xb + (ch * 4 + cc) * HWSZ + y1c * W_;
                    v10 = xc[x0c]; v11 = xc[x1c];
                }
                float s = w00 * v00 + w01 * v01 + w10 * v10 + w11 * v11;
                const float* wpc = wpk + cc * O_;
#pragma unroll
                for (int o = 0; o < O_; o++) acc[o] += s * wpc[o];
            }
        }
    }

    int obase = b * O_ * HWSZ + p;
#pragma unroll
    for (int o = 0; o < O_; o++)
        out[obase + o * HWSZ] = acc[o] + bias[o];
}

// ---------------------------------------------------------------------------
extern "C" void kernel_launch(void* const* d_in, const int* in_sizes, int n_in,
                              void* d_out, int out_size, void* d_ws, size_t ws_size,
                              hipStream_t stream) {
    const float* x     = (const float*)d_in[0];
    const float* w_off = (const float*)d_in[1];
    const float* b_off = (const float*)d_in[2];
    const float* w_mod = (const float*)d_in[3];
    const float* b_mod = (const float*)d_in[4];
    const float* w     = (const float*)d_in[5];
    const float* bias  = (const float*)d_in[6];
    float* out = (float*)d_out;

    const int nCoord = B_ * K2_ * HWSZ;   // 1,179,648
    float* pyA = (float*)d_ws;
    float* pxA = pyA + nCoord;
    float* mA  = pxA + nCoord;
    float* wt  = mA + nCoord;             // 36,864 floats
    float* wom = wt + K2_ * C_ * O_;      // 15,552 floats

    const int nPrep = K2_ * C_ * O_ + C_ * 243;
    hipLaunchKernelGGL(prep_weights_k, dim3((nPrep + 255) / 256), dim3(256),
                       0, stream, w, w_off, w_mod, wt, wom);
    hipLaunchKernelGGL(conv_offmask_k, dim3(1024), dim3(512), 0, stream,
                       x, wom, b_off, b_mod, pyA, pxA, mA);
    hipLaunchKernelGGL(sample_gemm_k, dim3(512), dim3(256), 0, stream,
                       x, pyA, pxA, mA, wt, bias, out);
}

// Round 3
// 321.586 us; speedup vs baseline: 2.1568x; 2.1568x over previous
//
#include <hip/hip_runtime.h>
#include <math.h>

#define H_ 128
#define W_ 128
#define C_ 64
#define O_ 64
#define B_ 8
#define K2_ 9
#define HWSZ (H_*W_)

// 8-byte vector load with only 4-byte alignment guarantee: gfx950 supports
// unaligned global access; let the backend pick the legal fast form
// (global_load_dwordx2) instead of lying about alignment.
typedef float f2u __attribute__((ext_vector_type(2), aligned(4)));

// ---------------------------------------------------------------------------
// Kernel P: weight prep.
//  wt  (K2, C, O)  : sample-GEMM weights, contiguous in o -> clean s_load.
//  wom (C, 27, 9)  : offset(18)+mask(9) conv weights contiguous per channel.
// ---------------------------------------------------------------------------
__global__ __launch_bounds__(256) void prep_weights_k(
    const float* __restrict__ w, const float* __restrict__ w_off,
    const float* __restrict__ w_mod, float* __restrict__ wt,
    float* __restrict__ wom) {
    int id = blockIdx.x * 256 + threadIdx.x;
    if (id < K2_ * C_ * O_) {              // id = k*C*O + c*O + o
        int o = id & (O_ - 1);
        int c = (id >> 6) & (C_ - 1);
        int k = id / (C_ * O_);
        wt[id] = w[(o * C_ + c) * K2_ + k];
    }
    int id2 = id - K2_ * C_ * O_;
    if (id2 >= 0 && id2 < C_ * 243) {      // id2 = c*243 + t*9 + k
        int k = id2 % 9;
        int tt = (id2 / 9) % 27;
        int c = id2 / 243;
        float v = (tt < 18) ? w_off[(tt * C_ + c) * K2_ + k]
                            : w_mod[((tt - 18) * C_ + c) * K2_ + k];
        wom[id2] = v;
    }
}

// ---------------------------------------------------------------------------
// Kernel A: 3x3 conv -> 18 offset + 9 mask channels, fused coord calc.
// (round-1 version, kept: non-B time 191 -> ~128 us)
// ---------------------------------------------------------------------------
__global__ __launch_bounds__(512) void conv_offmask_k(
    const float* __restrict__ x,
    const float* __restrict__ wom, const float* __restrict__ b_off,
    const float* __restrict__ b_mod,
    float* __restrict__ pyA, float* __restrict__ pxA, float* __restrict__ mA) {
    __shared__ float red[27 * 128];        // 13.8 KB

    int b     = blockIdx.x & 7;            // batch -> XCD (L2 locality)
    int strip = blockIdx.x >> 3;           // 0..127 : 1-row strip
    int tid   = threadIdx.x;
    int t     = tid & 127;                 // pixel within strip
    int q     = tid >> 7;                  // 0..3 -> channel quarter
    int c0    = __builtin_amdgcn_readfirstlane(q << 4);  // wave-uniform SGPR
    int p     = strip * 128 + t;
    int w     = p & (W_ - 1);
    int h     = p >> 7;

    int offs[9];
    float valid[9];
#pragma unroll
    for (int i = 0; i < 9; i++) {
        int dy = i / 3 - 1, dx = i % 3 - 1;
        int yy = h + dy, xx = w + dx;
        bool v = (yy >= 0 && yy < H_ && xx >= 0 && xx < W_);
        int yc = min(max(yy, 0), H_ - 1);
        int xc = min(max(xx, 0), W_ - 1);
        offs[i] = yc * W_ + xc;
        valid[i] = v ? 1.0f : 0.0f;
    }

    float acc[27];
#pragma unroll
    for (int o = 0; o < 27; o++) acc[o] = 0.0f;

    const float* xb = x + (b * C_ + c0) * HWSZ;

    float v[9];
#pragma unroll
    for (int i = 0; i < 9; i++) v[i] = xb[offs[i]] * valid[i];

    for (int c = 0; c < 16; c++) {
        const float* xn = xb + min(c + 1, 15) * HWSZ;
        float vn[9];
#pragma unroll
        for (int i = 0; i < 9; i++) vn[i] = xn[offs[i]] * valid[i];

        const float* wc = wom + (c0 + c) * 243;   // uniform -> s_load stream
#pragma unroll
        for (int o = 0; o < 27; o++) {
#pragma unroll
            for (int kk = 0; kk < 9; kk++) acc[o] += v[kk] * wc[o * 9 + kk];
        }
#pragma unroll
        for (int i = 0; i < 9; i++) v[i] = vn[i];
    }

    if (q == 3) {
#pragma unroll
        for (int o = 0; o < 27; o++) red[o * 128 + t] = acc[o];
    }
    __syncthreads();
    if (q == 2) {
#pragma unroll
        for (int o = 0; o < 27; o++) red[o * 128 + t] += acc[o];
    }
    __syncthreads();
    if (q == 1) {
#pragma unroll
        for (int o = 0; o < 27; o++) red[o * 128 + t] += acc[o];
    }
    __syncthreads();
    if (q == 0) {
#pragma unroll
        for (int k = 0; k < 9; k++) {
            float dy = acc[2 * k]     + red[(2 * k)     * 128 + t] + b_off[2 * k];
            float dx = acc[2 * k + 1] + red[(2 * k + 1) * 128 + t] + b_off[2 * k + 1];
            float mm = acc[18 + k]    + red[(18 + k)    * 128 + t] + b_mod[k];
            float mask = 2.0f / (1.0f + __expf(-mm));
            float py = dy + (float)h - 1.0f + (float)(k / 3);
            float px = dx + (float)w - 1.0f + (float)(k % 3);
            int idx = (b * 9 + k) * HWSZ + p;
            pyA[idx] = py;
            pxA[idx] = px;
            mA[idx] = mask;
        }
    }
}

// ---------------------------------------------------------------------------
// Kernel B v4: round-0 structure (512 thr, 2-way c-split, 64KB reduce --
// known 243us) + column-pair merged gathers.
// Rounds 0-2 lesson: time is linear in GATHER INSTRUCTION count (round-1:
// 2x gathers -> exactly 2x time, despite deep pipelining), i.e. the wall is
// per-instruction TA address-divergence serialization (~31 cyc/gather, TA
// ~98% busy in round 0) -- not miss latency, not LDS.
// Fix: the two x-taps of a bilinear row are adjacent columns -> ONE
// global_load_dwordx2 per row instead of two dword gathers (1152 -> 576
// gather instrs/thread). Edge cases (x0<0 / x0>W-2) are folded into the
// four bilinear weights ONCE PER K (8 cndmasks outside the c-loop):
//   x0=-1 : row contribution = w01*x[row][0]   -> a00=w01, a01=0
//   x0=127: row contribution = w00*x[row][127] -> a00=0,  a01=w00
// Loads always in-bounds: lc in [0,126], rows clamped to [0,127].
// c0 via readfirstlane -> weight reads stay s_load.
// ---------------------------------------------------------------------------
__global__ __launch_bounds__(512) void sample_gemm_k(
    const float* __restrict__ x,
    const float* __restrict__ pyA, const float* __restrict__ pxA,
    const float* __restrict__ mA, const float* __restrict__ wt,
    const float* __restrict__ bias, float* __restrict__ out) {
    __shared__ float red[O_ * 256];            // 64 KB

    int b     = blockIdx.x & 7;
    int strip = blockIdx.x >> 3;
    int tid   = threadIdx.x;
    int t     = tid & 255;
    int half  = tid >> 8;
    int c0    = __builtin_amdgcn_readfirstlane(half << 5);  // wave-uniform SGPR
    int p     = strip * 256 + t;

    float acc[O_];
#pragma unroll
    for (int o = 0; o < O_; o++) acc[o] = 0.0f;

    const float* xb = x + (b * C_ + c0) * HWSZ;

    for (int k = 0; k < 9; k++) {
        int idx = (b * 9 + k) * HWSZ + p;
        float py = pyA[idx];
        float px = pxA[idx];
        float m  = mA[idx];

        float y0f = floorf(py), x0f = floorf(px);
        float wy = py - y0f, wx = px - x0f;
        int y0 = (int)y0f, x0 = (int)x0f;
        int y1 = y0 + 1;
        float vy0 = (y0 >= 0 && y0 < H_) ? 1.0f : 0.0f;
        float vy1 = (y1 >= 0 && y1 < H_) ? 1.0f : 0.0f;
        float vx0 = (x0 >= 0 && x0 < W_) ? 1.0f : 0.0f;
        float vx1 = (x0 >= -1 && x0 < W_ - 1) ? 1.0f : 0.0f;
        int y0c = min(max(y0, 0), H_ - 1), y1c = min(max(y1, 0), H_ - 1);

        float w00 = (1.0f - wy) * (1.0f - wx) * vy0 * vx0 * m;
        float w01 = (1.0f - wy) * wx * vy0 * vx1 * m;
        float w10 = wy * (1.0f - wx) * vy1 * vx0 * m;
        float w11 = wy * wx * vy1 * vx1 * m;

        // column-pair merge: one 8B load per row covers both x-taps.
        int lc   = min(max(x0, 0), W_ - 2);    // 0..126, load [lc, lc+1]
        bool xlo = (x0 < 0);                   // v01 lives at f.x
        bool xhi = (x0 > W_ - 2);              // v00 lives at f.y
        float a00 = xhi ? 0.0f : (xlo ? w01 : w00);   // coeff on f.x, row0
        float a01 = xlo ? 0.0f : (xhi ? w00 : w01);   // coeff on f.y, row0
        float a10 = xhi ? 0.0f : (xlo ? w11 : w10);   // coeff on f.x, row1
        float a11 = xlo ? 0.0f : (xhi ? w10 : w11);   // coeff on f.y, row1

        int r0 = y0c * W_ + lc;
        int r1 = y1c * W_ + lc;

        const float* wp = wt + k * (C_ * O_) + c0 * O_;   // uniform -> s_load
        for (int c = 0; c < 32; c++) {
            const float* xc = xb + c * HWSZ;
            f2u f0 = *(const f2u*)(xc + r0);
            f2u f1 = *(const f2u*)(xc + r1);
            float s = a00 * f0.x + a01 * f0.y + a10 * f1.x + a11 * f1.y;
            const float* wpc = wp + c * O_;
#pragma unroll
            for (int o = 0; o < O_; o++) acc[o] += s * wpc[o];
        }
    }

    if (half) {
#pragma unroll
        for (int o = 0; o < O_; o++) red[o * 256 + t] = acc[o];  // stride-1: no conflicts
    }
    __syncthreads();
    if (!half) {
        int obase = b * O_ * HWSZ + p;
#pragma unroll
        for (int o = 0; o < O_; o++)
            out[obase + o * HWSZ] = acc[o] + red[o * 256 + t] + bias[o];
    }
}

// ---------------------------------------------------------------------------
extern "C" void kernel_launch(void* const* d_in, const int* in_sizes, int n_in,
                              void* d_out, int out_size, void* d_ws, size_t ws_size,
                              hipStream_t stream) {
    const float* x     = (const float*)d_in[0];
    const float* w_off = (const float*)d_in[1];
    const float* b_off = (const float*)d_in[2];
    const float* w_mod = (const float*)d_in[3];
    const float* b_mod = (const float*)d_in[4];
    const float* w     = (const float*)d_in[5];
    const float* bias  = (const float*)d_in[6];
    float* out = (float*)d_out;

    const int nCoord = B_ * K2_ * HWSZ;   // 1,179,648
    float* pyA = (float*)d_ws;
    float* pxA = pyA + nCoord;
    float* mA  = pxA + nCoord;
    float* wt  = mA + nCoord;             // 36,864 floats
    float* wom = wt + K2_ * C_ * O_;      // 15,552 floats

    const int nPrep = K2_ * C_ * O_ + C_ * 243;
    hipLaunchKernelGGL(prep_weights_k, dim3((nPrep + 255) / 256), dim3(256),
                       0, stream, w, w_off, w_mod, wt, wom);
    hipLaunchKernelGGL(conv_offmask_k, dim3(1024), dim3(512), 0, stream,
                       x, wom, b_off, b_mod, pyA, pxA, mA);
    hipLaunchKernelGGL(sample_gemm_k, dim3(512), dim3(512), 0, stream,
                       x, pyA, pxA, mA, wt, bias, out);
}